// Round 1
// baseline (1959.602 us; speedup 1.0000x reference)
//
#include <hip/hip_runtime.h>
#include <cstdint>
#include <cstddef>

#define N_NODES 50000
#define N_EDGES 800000
#define ET (N_EDGES + N_NODES)   // edges + self loops
#define D 128
#define NLAYERS 3
#define SLOPE 0.2f

// ---- monotonic float<->uint mapping for atomicMax-based segment max ----
__device__ __forceinline__ unsigned fmap(float f) {
    unsigned b = __float_as_uint(f);
    return (b & 0x80000000u) ? ~b : (b | 0x80000000u);
}
__device__ __forceinline__ float funmap(unsigned u) {
    return (u & 0x80000000u) ? __uint_as_float(u ^ 0x80000000u)
                             : __uint_as_float(~u);
}

// ---- dual GEMM: xl = h*Wl + bl, xr = h*Wr + br  (N x 128 @ 128 x 128) ----
// block = 256 threads, computes a 32-row x 128-col tile of both outputs.
__global__ void gemm2_kernel(const float* __restrict__ h,
                             const float* __restrict__ Wl, const float* __restrict__ bl,
                             const float* __restrict__ Wr, const float* __restrict__ br,
                             float* __restrict__ xl, float* __restrict__ xr, int n)
{
    __shared__ float hs[32][D];   // 16 KiB
    int t = threadIdx.x;
    int row0 = blockIdx.x * 32;

    // cooperative load of the 32x128 h tile (float4-vectorized, coalesced)
    #pragma unroll
    for (int i = 0; i < 4; i++) {
        int f4 = t + i * 256;            // 0..1023 float4 slots
        int r  = f4 >> 5;                // 32 float4 per row
        int c4 = f4 & 31;
        float4 v = make_float4(0.f, 0.f, 0.f, 0.f);
        if (row0 + r < n)
            v = *(const float4*)(h + (size_t)(row0 + r) * D + c4 * 4);
        *(float4*)&hs[r][c4 * 4] = v;
    }
    __syncthreads();

    int c  = t & 127;    // output column
    int rg = t >> 7;     // row group 0/1 (16 rows each)

    float accl[16], accr[16];
    #pragma unroll
    for (int r = 0; r < 16; r++) { accl[r] = 0.f; accr[r] = 0.f; }

    for (int k0 = 0; k0 < D; k0 += 4) {
        float wl0 = Wl[(k0 + 0) * D + c], wl1 = Wl[(k0 + 1) * D + c];
        float wl2 = Wl[(k0 + 2) * D + c], wl3 = Wl[(k0 + 3) * D + c];
        float wr0 = Wr[(k0 + 0) * D + c], wr1 = Wr[(k0 + 1) * D + c];
        float wr2 = Wr[(k0 + 2) * D + c], wr3 = Wr[(k0 + 3) * D + c];
        #pragma unroll
        for (int r = 0; r < 16; r++) {
            float4 hv = *(const float4*)&hs[rg * 16 + r][k0];  // wave-uniform addr (broadcast)
            accl[r] = fmaf(hv.x, wl0, accl[r]); accl[r] = fmaf(hv.y, wl1, accl[r]);
            accl[r] = fmaf(hv.z, wl2, accl[r]); accl[r] = fmaf(hv.w, wl3, accl[r]);
            accr[r] = fmaf(hv.x, wr0, accr[r]); accr[r] = fmaf(hv.y, wr1, accr[r]);
            accr[r] = fmaf(hv.z, wr2, accr[r]); accr[r] = fmaf(hv.w, wr3, accr[r]);
        }
    }

    float blc = bl[c], brc = br[c];
    #pragma unroll
    for (int r = 0; r < 16; r++) {
        int row = row0 + rg * 16 + r;
        if (row < n) {
            xl[(size_t)row * D + c] = accl[r] + blc;
            xr[(size_t)row * D + c] = accr[r] + brc;
        }
    }
}

// ---- per-edge GATv2 score + segment max (one wave64 per edge) ----
__global__ void edge_score_kernel(const float* __restrict__ xl,
                                  const float* __restrict__ xr,
                                  const float* __restrict__ att,
                                  const int* __restrict__ srcp,
                                  const int* __restrict__ dstp,
                                  float* __restrict__ score,
                                  unsigned* __restrict__ m_u)
{
    int w    = (int)((blockIdx.x * (size_t)blockDim.x + threadIdx.x) >> 6);
    int lane = threadIdx.x & 63;
    if (w >= ET) return;
    int s, dt;
    if (w < N_EDGES) { s = srcp[w]; dt = dstp[w]; }
    else             { s = w - N_EDGES; dt = s; }

    const float* xls = xl + (size_t)s  * D;
    const float* xrd = xr + (size_t)dt * D;
    float v0 = xls[lane]      + xrd[lane];
    float v1 = xls[lane + 64] + xrd[lane + 64];
    v0 = v0 > 0.f ? v0 : SLOPE * v0;
    v1 = v1 > 0.f ? v1 : SLOPE * v1;
    float sc = v0 * att[lane] + v1 * att[lane + 64];
    #pragma unroll
    for (int o = 32; o; o >>= 1) sc += __shfl_xor(sc, o, 64);
    if (lane == 0) {
        score[w] = sc;
        atomicMax(m_u + dt, fmap(sc));
    }
}

// ---- p = exp(score - m[dst]); denom = segment_sum(p) ----
__global__ void edge_exp_kernel(const float* __restrict__ score,
                                const int* __restrict__ dstp,
                                const unsigned* __restrict__ m_u,
                                float* __restrict__ p,
                                float* __restrict__ denom)
{
    int e = blockIdx.x * blockDim.x + threadIdx.x;
    if (e >= ET) return;
    int dt = (e < N_EDGES) ? dstp[e] : e - N_EDGES;
    float m  = funmap(m_u[dt]);
    float pv = __expf(score[e] - m);
    p[e] = pv;
    unsafeAtomicAdd(denom + dt, pv);
}

// ---- weighted scatter aggregate: hnew[dst] += alpha * xl[src] ----
__global__ void edge_aggr_kernel(const float* __restrict__ xl,
                                 const float* __restrict__ p,
                                 const float* __restrict__ denom,
                                 const int* __restrict__ srcp,
                                 const int* __restrict__ dstp,
                                 float* __restrict__ hnew)
{
    int w    = (int)((blockIdx.x * (size_t)blockDim.x + threadIdx.x) >> 6);
    int lane = threadIdx.x & 63;
    if (w >= ET) return;
    int s, dt;
    if (w < N_EDGES) { s = srcp[w]; dt = dstp[w]; }
    else             { s = w - N_EDGES; dt = s; }
    float alpha = p[w] / (denom[dt] + 1e-16f);
    const float* xls = xl + (size_t)s * D;
    float* out = hnew + (size_t)dt * D;
    unsafeAtomicAdd(out + lane,      xls[lane]      * alpha);
    unsafeAtomicAdd(out + lane + 64, xls[lane + 64] * alpha);
}

// ---- h = relu(hnew + bias) ----
__global__ void bias_relu_kernel(float* __restrict__ h,
                                 const float* __restrict__ bias, int total)
{
    int i = blockIdx.x * blockDim.x + threadIdx.x;
    if (i < total) {
        float v = h[i] + bias[i & (D - 1)];
        h[i] = v > 0.f ? v : 0.f;
    }
}

// ---- row log_softmax over 128 features (one wave64 per node) ----
__global__ void logsoftmax_kernel(const float* __restrict__ h,
                                  float* __restrict__ out)
{
    int w    = (int)((blockIdx.x * (size_t)blockDim.x + threadIdx.x) >> 6);
    int lane = threadIdx.x & 63;
    if (w >= N_NODES) return;
    float v0 = h[(size_t)w * D + lane];
    float v1 = h[(size_t)w * D + lane + 64];
    float mx = fmaxf(v0, v1);
    #pragma unroll
    for (int o = 32; o; o >>= 1) mx = fmaxf(mx, __shfl_xor(mx, o, 64));
    float se = __expf(v0 - mx) + __expf(v1 - mx);
    #pragma unroll
    for (int o = 32; o; o >>= 1) se += __shfl_xor(se, o, 64);
    float ls = logf(se) + mx;
    out[(size_t)w * D + lane]      = v0 - ls;
    out[(size_t)w * D + lane + 64] = v1 - ls;
}

extern "C" void kernel_launch(void* const* d_in, const int* in_sizes, int n_in,
                              void* d_out, int out_size, void* d_ws, size_t ws_size,
                              hipStream_t stream)
{
    const float* x    = (const float*)d_in[0];
    const int*   ei   = (const int*)  d_in[1];
    const float* Wl   = (const float*)d_in[2];
    const float* bl   = (const float*)d_in[3];
    const float* Wr   = (const float*)d_in[4];
    const float* br   = (const float*)d_in[5];
    const float* att  = (const float*)d_in[6];
    const float* bias = (const float*)d_in[7];
    float* out = (float*)d_out;

    const int* srcp = ei;            // edge_index[0]
    const int* dstp = ei + N_EDGES;  // edge_index[1]

    const size_t ND = (size_t)N_NODES * D;
    char* ws = (char*)d_ws;
    float*    xl    = (float*)ws;    ws += ND * sizeof(float);
    float*    xr    = (float*)ws;    ws += ND * sizeof(float);
    float*    buf0  = (float*)ws;    ws += ND * sizeof(float);
    float*    buf1  = (float*)ws;    ws += ND * sizeof(float);
    float*    score = (float*)ws;    ws += (size_t)ET * sizeof(float);
    float*    pbuf  = (float*)ws;    ws += (size_t)ET * sizeof(float);
    unsigned* m_u   = (unsigned*)ws; ws += (size_t)N_NODES * sizeof(unsigned);
    float*    denom = (float*)ws;    ws += (size_t)N_NODES * sizeof(float);

    const int gemmGrid  = (N_NODES + 31) / 32;
    const int waveGrid  = (int)(((size_t)ET * 64 + 255) / 256);
    const int edgeGrid  = (ET + 255) / 256;
    const int elemGrid  = (int)((ND + 255) / 256);
    const int smGrid    = (int)(((size_t)N_NODES * 64 + 255) / 256);

    for (int l = 0; l < NLAYERS; l++) {
        const float* hin  = (l == 0) ? x    : ((l == 1) ? buf0 : buf1);
        float*       hout = (l == 1) ? buf1 : buf0;

        hipMemsetAsync(m_u,   0, (size_t)N_NODES * sizeof(unsigned), stream);
        hipMemsetAsync(denom, 0, (size_t)N_NODES * sizeof(float),    stream);
        hipMemsetAsync(hout,  0, ND * sizeof(float),                 stream);

        gemm2_kernel<<<gemmGrid, 256, 0, stream>>>(
            hin, Wl + (size_t)l * D * D, bl + (size_t)l * D,
                 Wr + (size_t)l * D * D, br + (size_t)l * D, xl, xr, N_NODES);

        edge_score_kernel<<<waveGrid, 256, 0, stream>>>(
            xl, xr, att + (size_t)l * D, srcp, dstp, score, m_u);

        edge_exp_kernel<<<edgeGrid, 256, 0, stream>>>(
            score, dstp, m_u, pbuf, denom);

        edge_aggr_kernel<<<waveGrid, 256, 0, stream>>>(
            xl, pbuf, denom, srcp, dstp, hout);

        bias_relu_kernel<<<elemGrid, 256, 0, stream>>>(
            hout, bias + (size_t)l * D, (int)ND);
    }

    logsoftmax_kernel<<<smGrid, 256, 0, stream>>>(buf0, out);
}

// Round 2
// 702.832 us; speedup vs baseline: 2.7882x; 2.7882x over previous
//
#include <hip/hip_runtime.h>
#include <cstdint>
#include <cstddef>

#define N_NODES 50000
#define N_EDGES 800000
#define ET (N_EDGES + N_NODES)   // edges + self loops
#define D 128
#define NLAYERS 3
#define SLOPE 0.2f

// ---- dual GEMM: xl = h*Wl + bl, xr = h*Wr + br  (N x 128 @ 128 x 128) ----
__global__ void gemm2_kernel(const float* __restrict__ h,
                             const float* __restrict__ Wl, const float* __restrict__ bl,
                             const float* __restrict__ Wr, const float* __restrict__ br,
                             float* __restrict__ xl, float* __restrict__ xr, int n)
{
    __shared__ float hs[32][D];   // 16 KiB
    int t = threadIdx.x;
    int row0 = blockIdx.x * 32;

    #pragma unroll
    for (int i = 0; i < 4; i++) {
        int f4 = t + i * 256;
        int r  = f4 >> 5;
        int c4 = f4 & 31;
        float4 v = make_float4(0.f, 0.f, 0.f, 0.f);
        if (row0 + r < n)
            v = *(const float4*)(h + (size_t)(row0 + r) * D + c4 * 4);
        *(float4*)&hs[r][c4 * 4] = v;
    }
    __syncthreads();

    int c  = t & 127;
    int rg = t >> 7;

    float accl[16], accr[16];
    #pragma unroll
    for (int r = 0; r < 16; r++) { accl[r] = 0.f; accr[r] = 0.f; }

    for (int k0 = 0; k0 < D; k0 += 4) {
        float wl0 = Wl[(k0 + 0) * D + c], wl1 = Wl[(k0 + 1) * D + c];
        float wl2 = Wl[(k0 + 2) * D + c], wl3 = Wl[(k0 + 3) * D + c];
        float wr0 = Wr[(k0 + 0) * D + c], wr1 = Wr[(k0 + 1) * D + c];
        float wr2 = Wr[(k0 + 2) * D + c], wr3 = Wr[(k0 + 3) * D + c];
        #pragma unroll
        for (int r = 0; r < 16; r++) {
            float4 hv = *(const float4*)&hs[rg * 16 + r][k0];
            accl[r] = fmaf(hv.x, wl0, accl[r]); accl[r] = fmaf(hv.y, wl1, accl[r]);
            accl[r] = fmaf(hv.z, wl2, accl[r]); accl[r] = fmaf(hv.w, wl3, accl[r]);
            accr[r] = fmaf(hv.x, wr0, accr[r]); accr[r] = fmaf(hv.y, wr1, accr[r]);
            accr[r] = fmaf(hv.z, wr2, accr[r]); accr[r] = fmaf(hv.w, wr3, accr[r]);
        }
    }

    float blc = bl[c], brc = br[c];
    #pragma unroll
    for (int r = 0; r < 16; r++) {
        int row = row0 + rg * 16 + r;
        if (row < n) {
            xl[(size_t)row * D + c] = accl[r] + blc;
            xr[(size_t)row * D + c] = accr[r] + brc;
        }
    }
}

// ================= CSR build (once per launch; edge set is layer-invariant) ==========
__global__ void degree_kernel(const int* __restrict__ dstp, int* __restrict__ deg)
{
    int e = blockIdx.x * blockDim.x + threadIdx.x;
    if (e >= ET) return;
    int dt = (e < N_EDGES) ? dstp[e] : e - N_EDGES;
    atomicAdd(deg + dt, 1);
}

// single-block exclusive scan of deg[N] -> off[N+1]
__global__ void scan_kernel(const int* __restrict__ deg, int* __restrict__ off)
{
    __shared__ int tmp[1024];
    __shared__ int carry;
    if (threadIdx.x == 0) carry = 0;
    __syncthreads();
    for (int base = 0; base < N_NODES; base += 1024) {
        int i = base + threadIdx.x;
        int v = (i < N_NODES) ? deg[i] : 0;
        tmp[threadIdx.x] = v;
        __syncthreads();
        #pragma unroll
        for (int o = 1; o < 1024; o <<= 1) {
            int t = (threadIdx.x >= o) ? tmp[threadIdx.x - o] : 0;
            __syncthreads();
            tmp[threadIdx.x] += t;
            __syncthreads();
        }
        int incl = tmp[threadIdx.x];
        if (i < N_NODES) off[i] = carry + incl - v;   // exclusive
        __syncthreads();
        if (threadIdx.x == 1023) carry += tmp[1023];
        __syncthreads();
    }
    if (threadIdx.x == 0) off[N_NODES] = carry;
}

// scatter src node ids into CSR slots (order within a node irrelevant)
__global__ void scatter_kernel(const int* __restrict__ srcp, const int* __restrict__ dstp,
                               int* __restrict__ cursor, int* __restrict__ esrc)
{
    int e = blockIdx.x * blockDim.x + threadIdx.x;
    if (e >= ET) return;
    int s, dt;
    if (e < N_EDGES) { s = srcp[e]; dt = dstp[e]; }
    else             { s = e - N_EDGES; dt = s; }
    int pos = atomicAdd(cursor + dt, 1);
    esrc[pos] = s;
}

// ============ fused per-node GATv2: online softmax + weighted gather aggregate =======
// one wave64 per dst node; LAST=1 additionally fuses row log_softmax
template <int LAST>
__global__ void node_attn_kernel(const float* __restrict__ xl,
                                 const float* __restrict__ xr,
                                 const float* __restrict__ att,
                                 const float* __restrict__ bias,
                                 const int* __restrict__ off,
                                 const int* __restrict__ esrc,
                                 float* __restrict__ hout)
{
    int i    = (int)((blockIdx.x * (size_t)blockDim.x + threadIdx.x) >> 6);
    int lane = threadIdx.x & 63;
    if (i >= N_NODES) return;

    float a0 = att[lane], a1 = att[lane + 64];
    const float* xri = xr + (size_t)i * D;
    float r0 = xri[lane], r1 = xri[lane + 64];

    float m = -1e30f, l = 0.f, acc0 = 0.f, acc1 = 0.f;

    int kEnd = off[i + 1];
    for (int k = off[i]; k < kEnd; ++k) {
        int s = esrc[k];
        const float* xls = xl + (size_t)s * D;
        float x0 = xls[lane], x1 = xls[lane + 64];
        float v0 = x0 + r0; v0 = v0 > 0.f ? v0 : SLOPE * v0;
        float v1 = x1 + r1; v1 = v1 > 0.f ? v1 : SLOPE * v1;
        float sc = v0 * a0 + v1 * a1;
        #pragma unroll
        for (int o = 32; o; o >>= 1) sc += __shfl_xor(sc, o, 64);
        float mn = fmaxf(m, sc);
        float p  = __expf(sc - mn);
        float f  = __expf(m - mn);      // first iter: exp(-inf)=0
        l    = l * f + p;
        acc0 = acc0 * f + p * x0;
        acc1 = acc1 * f + p * x1;
        m = mn;
    }

    float inv = 1.f / (l + 1e-16f);
    float h0 = acc0 * inv + bias[lane];
    float h1 = acc1 * inv + bias[lane + 64];
    h0 = h0 > 0.f ? h0 : 0.f;
    h1 = h1 > 0.f ? h1 : 0.f;

    if (LAST) {
        float mx = fmaxf(h0, h1);
        #pragma unroll
        for (int o = 32; o; o >>= 1) mx = fmaxf(mx, __shfl_xor(mx, o, 64));
        float se = __expf(h0 - mx) + __expf(h1 - mx);
        #pragma unroll
        for (int o = 32; o; o >>= 1) se += __shfl_xor(se, o, 64);
        float ls = logf(se) + mx;
        h0 -= ls;
        h1 -= ls;
    }

    hout[(size_t)i * D + lane]      = h0;
    hout[(size_t)i * D + lane + 64] = h1;
}

extern "C" void kernel_launch(void* const* d_in, const int* in_sizes, int n_in,
                              void* d_out, int out_size, void* d_ws, size_t ws_size,
                              hipStream_t stream)
{
    const float* x    = (const float*)d_in[0];
    const int*   ei   = (const int*)  d_in[1];
    const float* Wl   = (const float*)d_in[2];
    const float* bl   = (const float*)d_in[3];
    const float* Wr   = (const float*)d_in[4];
    const float* br   = (const float*)d_in[5];
    const float* att  = (const float*)d_in[6];
    const float* bias = (const float*)d_in[7];
    float* out = (float*)d_out;

    const int* srcp = ei;
    const int* dstp = ei + N_EDGES;

    const size_t ND = (size_t)N_NODES * D;
    char* ws = (char*)d_ws;
    float* xl   = (float*)ws; ws += ND * sizeof(float);
    float* xr   = (float*)ws; ws += ND * sizeof(float);
    float* buf0 = (float*)ws; ws += ND * sizeof(float);
    float* buf1 = (float*)ws; ws += ND * sizeof(float);
    int* deg    = (int*)ws;   ws += (size_t)N_NODES * sizeof(int);
    int* off    = (int*)ws;   ws += (size_t)(N_NODES + 1) * sizeof(int);
    int* cursor = (int*)ws;   ws += (size_t)N_NODES * sizeof(int);
    int* esrc   = (int*)ws;   ws += (size_t)ET * sizeof(int);

    const int edgeGrid = (ET + 255) / 256;
    const int gemmGrid = (N_NODES + 31) / 32;
    const int nodeGrid = (N_NODES + 3) / 4;   // 4 waves per 256-block, 1 node/wave

    // ---- CSR build (once; edge structure identical across layers) ----
    hipMemsetAsync(deg, 0, (size_t)N_NODES * sizeof(int), stream);
    degree_kernel<<<edgeGrid, 256, 0, stream>>>(dstp, deg);
    scan_kernel<<<1, 1024, 0, stream>>>(deg, off);
    hipMemcpyAsync(cursor, off, (size_t)N_NODES * sizeof(int),
                   hipMemcpyDeviceToDevice, stream);
    scatter_kernel<<<edgeGrid, 256, 0, stream>>>(srcp, dstp, cursor, esrc);

    // ---- layers ----
    for (int l = 0; l < NLAYERS; l++) {
        const float* hin  = (l == 0) ? x    : ((l == 1) ? buf0 : buf1);
        float*       hout = (l == 1) ? buf1 : buf0;

        gemm2_kernel<<<gemmGrid, 256, 0, stream>>>(
            hin, Wl + (size_t)l * D * D, bl + (size_t)l * D,
                 Wr + (size_t)l * D * D, br + (size_t)l * D, xl, xr, N_NODES);

        if (l == NLAYERS - 1) {
            node_attn_kernel<1><<<nodeGrid, 256, 0, stream>>>(
                xl, xr, att + (size_t)l * D, bias + (size_t)l * D, off, esrc, out);
        } else {
            node_attn_kernel<0><<<nodeGrid, 256, 0, stream>>>(
                xl, xr, att + (size_t)l * D, bias + (size_t)l * D, off, esrc, hout);
        }
    }
}

// Round 3
// 602.041 us; speedup vs baseline: 3.2549x; 1.1674x over previous
//
#include <hip/hip_runtime.h>
#include <cstdint>
#include <cstddef>

#define N_NODES 50000
#define N_EDGES 800000
#define ET (N_EDGES + N_NODES)   // edges + self loops
#define D 128
#define NLAYERS 3
#define SLOPE 0.2f

typedef __bf16 bf16x8 __attribute__((ext_vector_type(8)));
typedef float  f32x4  __attribute__((ext_vector_type(4)));

// ---- bf16 split helpers (round-to-nearest-even) ----
__device__ __forceinline__ unsigned short f2bf_rne(float v) {
    unsigned u = __float_as_uint(v);
    u += 0x7fffu + ((u >> 16) & 1u);
    return (unsigned short)(u >> 16);
}
__device__ __forceinline__ float bf2f(unsigned short h) {
    return __uint_as_float(((unsigned)h) << 16);
}

// ================= prep: split fp32 -> bf16 hi/lo ==================
__global__ void split_x_kernel(const float* __restrict__ x,
                               unsigned short* __restrict__ hhi,
                               unsigned short* __restrict__ hlo)
{
    int i = blockIdx.x * blockDim.x + threadIdx.x;   // float4 index
    if (i >= (N_NODES * D) / 4) return;
    float4 v = ((const float4*)x)[i];
    unsigned short h0 = f2bf_rne(v.x), h1 = f2bf_rne(v.y);
    unsigned short h2 = f2bf_rne(v.z), h3 = f2bf_rne(v.w);
    unsigned short l0 = f2bf_rne(v.x - bf2f(h0)), l1 = f2bf_rne(v.y - bf2f(h1));
    unsigned short l2 = f2bf_rne(v.z - bf2f(h2)), l3 = f2bf_rne(v.w - bf2f(h3));
    uint2 hw, lw;
    hw.x = (unsigned)h0 | ((unsigned)h1 << 16);
    hw.y = (unsigned)h2 | ((unsigned)h3 << 16);
    lw.x = (unsigned)l0 | ((unsigned)l1 << 16);
    lw.y = (unsigned)l2 | ((unsigned)l3 << 16);
    ((uint2*)hhi)[i] = hw;
    ((uint2*)hlo)[i] = lw;
}

// transpose + split weights: W[l][k][n] -> Wt[l][n][k] hi/lo for both mats
__global__ void prep_weights_kernel(const float* __restrict__ Wl,
                                    const float* __restrict__ Wr,
                                    unsigned short* __restrict__ wlh, unsigned short* __restrict__ wll,
                                    unsigned short* __restrict__ wrh, unsigned short* __restrict__ wrl)
{
    int idx = blockIdx.x * blockDim.x + threadIdx.x;
    if (idx >= NLAYERS * D * D) return;
    int l   = idx / (D * D);
    int rem = idx - l * D * D;
    int kk  = rem / D;
    int nn  = rem - kk * D;
    int tp  = l * D * D + nn * D + kk;
    float v = Wl[idx];
    unsigned short h = f2bf_rne(v);
    wlh[tp] = h;
    wll[tp] = f2bf_rne(v - bf2f(h));
    v = Wr[idx];
    h = f2bf_rne(v);
    wrh[tp] = h;
    wrl[tp] = f2bf_rne(v - bf2f(h));
}

// ================= CSR build ==================
__global__ void degree_kernel(const int* __restrict__ dstp, int* __restrict__ deg)
{
    int e = blockIdx.x * blockDim.x + threadIdx.x;
    if (e >= ET) return;
    int dt = (e < N_EDGES) ? dstp[e] : e - N_EDGES;
    atomicAdd(deg + dt, 1);
}

__global__ void scan_kernel(const int* __restrict__ deg, int* __restrict__ off)
{
    __shared__ int tmp[1024];
    __shared__ int carry;
    if (threadIdx.x == 0) carry = 0;
    __syncthreads();
    for (int base = 0; base < N_NODES; base += 1024) {
        int i = base + threadIdx.x;
        int v = (i < N_NODES) ? deg[i] : 0;
        tmp[threadIdx.x] = v;
        __syncthreads();
        #pragma unroll
        for (int o = 1; o < 1024; o <<= 1) {
            int t = (threadIdx.x >= o) ? tmp[threadIdx.x - o] : 0;
            __syncthreads();
            tmp[threadIdx.x] += t;
            __syncthreads();
        }
        int incl = tmp[threadIdx.x];
        if (i < N_NODES) off[i] = carry + incl - v;
        __syncthreads();
        if (threadIdx.x == 1023) carry += tmp[1023];
        __syncthreads();
    }
    if (threadIdx.x == 0) off[N_NODES] = carry;
}

__global__ void scatter_kernel(const int* __restrict__ srcp, const int* __restrict__ dstp,
                               int* __restrict__ cursor, int* __restrict__ esrc)
{
    int e = blockIdx.x * blockDim.x + threadIdx.x;
    if (e >= ET) return;
    int s, dt;
    if (e < N_EDGES) { s = srcp[e]; dt = dstp[e]; }
    else             { s = e - N_EDGES; dt = s; }
    int pos = atomicAdd(cursor + dt, 1);
    esrc[pos] = s;
}

// ============ MFMA dual GEMM, 3-term bf16x2 (~fp32 accuracy) ============
// xl = h*Wl + bl, xr = h*Wr + br.  One wave per 16-row strip, all 128 cols.
__global__ void gemm_mfma_kernel(const unsigned short* __restrict__ hhi,
                                 const unsigned short* __restrict__ hlo,
                                 const unsigned short* __restrict__ wlh,
                                 const unsigned short* __restrict__ wll,
                                 const unsigned short* __restrict__ wrh,
                                 const unsigned short* __restrict__ wrl,
                                 const float* __restrict__ bl, const float* __restrict__ br,
                                 float* __restrict__ xl, float* __restrict__ xr, int n)
{
    int lane = threadIdx.x & 63;
    int wid  = threadIdx.x >> 6;
    int m0 = (blockIdx.x * 4 + wid) * 16;
    if (m0 >= n) return;
    int gl = lane & 15;
    int kg = lane >> 4;

    // A fragments: A[m][k], m = lane&15, k = (lane>>4)*8 + e
    int arow = m0 + gl; if (arow >= n) arow = n - 1;
    const unsigned short* ah = hhi + (size_t)arow * D + kg * 8;
    const unsigned short* al = hlo + (size_t)arow * D + kg * 8;
    bf16x8 Ah[4], Al[4];
    #pragma unroll
    for (int ks = 0; ks < 4; ks++) {
        Ah[ks] = *(const bf16x8*)(ah + ks * 32);
        Al[ks] = *(const bf16x8*)(al + ks * 32);
    }

    #pragma unroll
    for (int nt = 0; nt < 8; nt++) {
        int n0 = nt * 16;
        // B fragments from transposed weights Wt[n][k]: n = lane&15, k = kg*8+e
        size_t boff = (size_t)(n0 + gl) * D + kg * 8;
        f32x4 accl = {0.f, 0.f, 0.f, 0.f};
        f32x4 accr = {0.f, 0.f, 0.f, 0.f};
        #pragma unroll
        for (int ks = 0; ks < 4; ks++) {
            bf16x8 Blh = *(const bf16x8*)(wlh + boff + ks * 32);
            bf16x8 Bll = *(const bf16x8*)(wll + boff + ks * 32);
            bf16x8 Brh = *(const bf16x8*)(wrh + boff + ks * 32);
            bf16x8 Brl = *(const bf16x8*)(wrl + boff + ks * 32);
            accl = __builtin_amdgcn_mfma_f32_16x16x32_bf16(Ah[ks], Blh, accl, 0, 0, 0);
            accl = __builtin_amdgcn_mfma_f32_16x16x32_bf16(Al[ks], Blh, accl, 0, 0, 0);
            accl = __builtin_amdgcn_mfma_f32_16x16x32_bf16(Ah[ks], Bll, accl, 0, 0, 0);
            accr = __builtin_amdgcn_mfma_f32_16x16x32_bf16(Ah[ks], Brh, accr, 0, 0, 0);
            accr = __builtin_amdgcn_mfma_f32_16x16x32_bf16(Al[ks], Brh, accr, 0, 0, 0);
            accr = __builtin_amdgcn_mfma_f32_16x16x32_bf16(Ah[ks], Brl, accr, 0, 0, 0);
        }
        float blc = bl[n0 + gl], brc = br[n0 + gl];
        // C/D layout: col = lane&15, row = (lane>>4)*4 + reg   [verified]
        #pragma unroll
        for (int r = 0; r < 4; r++) {
            int row = m0 + kg * 4 + r;
            if (row < n) {
                xl[(size_t)row * D + n0 + gl] = accl[r] + blc;
                xr[(size_t)row * D + n0 + gl] = accr[r] + brc;
            }
        }
    }
}

// ============ fused per-node GATv2: 4 edges/wave, 16 lanes/edge ============
// LAST=1: fuse log_softmax, write fp32 out. LAST=0: write h as bf16 hi/lo.
template <int LAST>
__global__ void node_attn_kernel(const float* __restrict__ xl,
                                 const float* __restrict__ xr,
                                 const float* __restrict__ att,
                                 const float* __restrict__ bias,
                                 const int* __restrict__ off,
                                 const int* __restrict__ esrc,
                                 float* __restrict__ outF,
                                 unsigned short* __restrict__ hhi,
                                 unsigned short* __restrict__ hlo)
{
    int i    = (int)((blockIdx.x * (size_t)blockDim.x + threadIdx.x) >> 6);
    int lane = threadIdx.x & 63;
    if (i >= N_NODES) return;
    int g  = lane >> 4;     // edge slot 0..3
    int gl = lane & 15;     // lane within group
    int fb = gl * 8;        // this lane's 8 features

    float4 aa = *(const float4*)(att + fb);
    float4 ab = *(const float4*)(att + fb + 4);
    const float* xri = xr + (size_t)i * D + fb;
    float4 ra = *(const float4*)(xri);
    float4 rb = *(const float4*)(xri + 4);

    float m = -1e30f, l = 0.f;
    float acc[8];
    #pragma unroll
    for (int e = 0; e < 8; e++) acc[e] = 0.f;

    int k    = off[i];
    int kEnd = off[i + 1];

    // prologue: load edge k+g
    int kk = k + g;
    bool valid = kk < kEnd;
    {
        int s = esrc[valid ? kk : kEnd - 1];
        // fall through to loads below via pointer
        const float* xls = xl + (size_t)s * D + fb;
        // loaded into xa/xb below
        (void)xls;
    }
    int s0 = esrc[valid ? kk : kEnd - 1];
    const float* xls0 = xl + (size_t)s0 * D + fb;
    float4 xa = *(const float4*)(xls0);
    float4 xb = *(const float4*)(xls0 + 4);

    while (k < kEnd) {
        int kn = k + 4;
        float4 nxa = xa, nxb = xb;
        bool nvalid = false;
        if (kn < kEnd) {                       // wave-uniform branch: prefetch
            int nkk = kn + g;
            nvalid = nkk < kEnd;
            int ns = esrc[nvalid ? nkk : kEnd - 1];
            const float* nx = xl + (size_t)ns * D + fb;
            nxa = *(const float4*)(nx);
            nxb = *(const float4*)(nx + 4);
        }
        // score partial over this lane's 8 features
        float v, sc;
        v = xa.x + ra.x; v = v > 0.f ? v : SLOPE * v; sc  = v * aa.x;
        v = xa.y + ra.y; v = v > 0.f ? v : SLOPE * v; sc += v * aa.y;
        v = xa.z + ra.z; v = v > 0.f ? v : SLOPE * v; sc += v * aa.z;
        v = xa.w + ra.w; v = v > 0.f ? v : SLOPE * v; sc += v * aa.w;
        v = xb.x + rb.x; v = v > 0.f ? v : SLOPE * v; sc += v * ab.x;
        v = xb.y + rb.y; v = v > 0.f ? v : SLOPE * v; sc += v * ab.y;
        v = xb.z + rb.z; v = v > 0.f ? v : SLOPE * v; sc += v * ab.z;
        v = xb.w + rb.w; v = v > 0.f ? v : SLOPE * v; sc += v * ab.w;
        // reduce over the 16 lanes of this group
        sc += __shfl_xor(sc, 1, 64);
        sc += __shfl_xor(sc, 2, 64);
        sc += __shfl_xor(sc, 4, 64);
        sc += __shfl_xor(sc, 8, 64);
        // online softmax update
        float mn = fmaxf(m, sc);
        float p  = valid ? __expf(sc - mn) : 0.f;
        float f  = __expf(m - mn);
        l = l * f + p;
        acc[0] = acc[0] * f + p * xa.x;
        acc[1] = acc[1] * f + p * xa.y;
        acc[2] = acc[2] * f + p * xa.z;
        acc[3] = acc[3] * f + p * xa.w;
        acc[4] = acc[4] * f + p * xb.x;
        acc[5] = acc[5] * f + p * xb.y;
        acc[6] = acc[6] * f + p * xb.z;
        acc[7] = acc[7] * f + p * xb.w;
        m = mn;
        xa = nxa; xb = nxb; valid = nvalid;
        k = kn;
    }

    // merge the 4 groups' online-softmax states (xor 16, then 32)
    #pragma unroll
    for (int o = 16; o <= 32; o <<= 1) {
        float mo  = __shfl_xor(m, o, 64);
        float lo2 = __shfl_xor(l, o, 64);
        float mn  = fmaxf(m, mo);
        float f1  = __expf(m - mn);
        float f2  = __expf(mo - mn);
        l = l * f1 + lo2 * f2;
        #pragma unroll
        for (int e = 0; e < 8; e++) {
            float ao = __shfl_xor(acc[e], o, 64);
            acc[e] = acc[e] * f1 + ao * f2;
        }
        m = mn;
    }

    float inv = 1.f / (l + 1e-16f);
    const float* bp = bias + fb;
    float4 ba = *(const float4*)(bp);
    float4 bb = *(const float4*)(bp + 4);
    float hv[8];
    hv[0] = fmaxf(acc[0] * inv + ba.x, 0.f);
    hv[1] = fmaxf(acc[1] * inv + ba.y, 0.f);
    hv[2] = fmaxf(acc[2] * inv + ba.z, 0.f);
    hv[3] = fmaxf(acc[3] * inv + ba.w, 0.f);
    hv[4] = fmaxf(acc[4] * inv + bb.x, 0.f);
    hv[5] = fmaxf(acc[5] * inv + bb.y, 0.f);
    hv[6] = fmaxf(acc[6] * inv + bb.z, 0.f);
    hv[7] = fmaxf(acc[7] * inv + bb.w, 0.f);

    if (LAST) {
        float mx = hv[0];
        #pragma unroll
        for (int e = 1; e < 8; e++) mx = fmaxf(mx, hv[e]);
        mx = fmaxf(mx, __shfl_xor(mx, 1, 64));
        mx = fmaxf(mx, __shfl_xor(mx, 2, 64));
        mx = fmaxf(mx, __shfl_xor(mx, 4, 64));
        mx = fmaxf(mx, __shfl_xor(mx, 8, 64));
        float se = 0.f;
        #pragma unroll
        for (int e = 0; e < 8; e++) se += __expf(hv[e] - mx);
        se += __shfl_xor(se, 1, 64);
        se += __shfl_xor(se, 2, 64);
        se += __shfl_xor(se, 4, 64);
        se += __shfl_xor(se, 8, 64);
        float ls = logf(se) + mx;
        if (g == 0) {
            float4 o0 = make_float4(hv[0] - ls, hv[1] - ls, hv[2] - ls, hv[3] - ls);
            float4 o1 = make_float4(hv[4] - ls, hv[5] - ls, hv[6] - ls, hv[7] - ls);
            float* dst = outF + (size_t)i * D + fb;
            *(float4*)(dst)     = o0;
            *(float4*)(dst + 4) = o1;
        }
    } else {
        if (g < 2) {
            unsigned short w16[8];
            #pragma unroll
            for (int e = 0; e < 8; e++) {
                unsigned short hb = f2bf_rne(hv[e]);
                if (g == 0) w16[e] = hb;
                else        w16[e] = f2bf_rne(hv[e] - bf2f(hb));
            }
            uint4 pk;
            pk.x = (unsigned)w16[0] | ((unsigned)w16[1] << 16);
            pk.y = (unsigned)w16[2] | ((unsigned)w16[3] << 16);
            pk.z = (unsigned)w16[4] | ((unsigned)w16[5] << 16);
            pk.w = (unsigned)w16[6] | ((unsigned)w16[7] << 16);
            unsigned short* dst = (g == 0 ? hhi : hlo) + (size_t)i * D + fb;
            *(uint4*)dst = pk;
        }
    }
}

extern "C" void kernel_launch(void* const* d_in, const int* in_sizes, int n_in,
                              void* d_out, int out_size, void* d_ws, size_t ws_size,
                              hipStream_t stream)
{
    const float* x    = (const float*)d_in[0];
    const int*   ei   = (const int*)  d_in[1];
    const float* Wl   = (const float*)d_in[2];
    const float* bl   = (const float*)d_in[3];
    const float* Wr   = (const float*)d_in[4];
    const float* br   = (const float*)d_in[5];
    const float* att  = (const float*)d_in[6];
    const float* bias = (const float*)d_in[7];
    float* out = (float*)d_out;

    const int* srcp = ei;
    const int* dstp = ei + N_EDGES;

    const size_t ND = (size_t)N_NODES * D;
    const size_t WSZ = (size_t)NLAYERS * D * D;
    char* ws = (char*)d_ws;
    float* xl  = (float*)ws;          ws += ND * sizeof(float);
    float* xr  = (float*)ws;          ws += ND * sizeof(float);
    unsigned short* hhi = (unsigned short*)ws; ws += ND * sizeof(unsigned short);
    unsigned short* hlo = (unsigned short*)ws; ws += ND * sizeof(unsigned short);
    unsigned short* wlh = (unsigned short*)ws; ws += WSZ * sizeof(unsigned short);
    unsigned short* wll = (unsigned short*)ws; ws += WSZ * sizeof(unsigned short);
    unsigned short* wrh = (unsigned short*)ws; ws += WSZ * sizeof(unsigned short);
    unsigned short* wrl = (unsigned short*)ws; ws += WSZ * sizeof(unsigned short);
    int* deg    = (int*)ws;  ws += (size_t)N_NODES * sizeof(int);
    int* off    = (int*)ws;  ws += (size_t)(N_NODES + 1) * sizeof(int);
    int* cursor = (int*)ws;  ws += (size_t)N_NODES * sizeof(int);
    int* esrc   = (int*)ws;  ws += (size_t)ET * sizeof(int);

    const int splitGrid = (int)((ND / 4 + 255) / 256);
    const int wGrid     = (int)((WSZ + 255) / 256);
    const int edgeGrid  = (ET + 255) / 256;
    const int gemmGrid  = (N_NODES + 63) / 64;
    const int nodeGrid  = (N_NODES + 3) / 4;

    // prep (independent of CSR)
    split_x_kernel<<<splitGrid, 256, 0, stream>>>(x, hhi, hlo);
    prep_weights_kernel<<<wGrid, 256, 0, stream>>>(Wl, Wr, wlh, wll, wrh, wrl);

    // CSR build
    hipMemsetAsync(deg, 0, (size_t)N_NODES * sizeof(int), stream);
    degree_kernel<<<edgeGrid, 256, 0, stream>>>(dstp, deg);
    scan_kernel<<<1, 1024, 0, stream>>>(deg, off);
    hipMemcpyAsync(cursor, off, (size_t)N_NODES * sizeof(int),
                   hipMemcpyDeviceToDevice, stream);
    scatter_kernel<<<edgeGrid, 256, 0, stream>>>(srcp, dstp, cursor, esrc);

    for (int l = 0; l < NLAYERS; l++) {
        size_t wOff = (size_t)l * D * D;
        gemm_mfma_kernel<<<gemmGrid, 256, 0, stream>>>(
            hhi, hlo, wlh + wOff, wll + wOff, wrh + wOff, wrl + wOff,
            bl + (size_t)l * D, br + (size_t)l * D, xl, xr, N_NODES);

        if (l == NLAYERS - 1) {
            node_attn_kernel<1><<<nodeGrid, 256, 0, stream>>>(
                xl, xr, att + (size_t)l * D, bias + (size_t)l * D,
                off, esrc, out, nullptr, nullptr);
        } else {
            node_attn_kernel<0><<<nodeGrid, 256, 0, stream>>>(
                xl, xr, att + (size_t)l * D, bias + (size_t)l * D,
                off, esrc, nullptr, hhi, hlo);
        }
    }
}

// Round 4
// 481.138 us; speedup vs baseline: 4.0728x; 1.2513x over previous
//
#include <hip/hip_runtime.h>
#include <cstdint>
#include <cstddef>

#define N_NODES 50000
#define N_EDGES 800000
#define ET (N_EDGES + N_NODES)   // edges + self loops
#define D 128
#define NLAYERS 3
#define SLOPE 0.2f
#define NB_SCAN ((N_NODES + 1023) / 1024)   // 49 blocks

typedef __bf16 bf16x8 __attribute__((ext_vector_type(8)));
typedef float  f32x4  __attribute__((ext_vector_type(4)));

// ---- bf16 split helpers (round-to-nearest-even) ----
__device__ __forceinline__ unsigned short f2bf_rne(float v) {
    unsigned u = __float_as_uint(v);
    u += 0x7fffu + ((u >> 16) & 1u);
    return (unsigned short)(u >> 16);
}
__device__ __forceinline__ float bf2f(unsigned short h) {
    return __uint_as_float(((unsigned)h) << 16);
}

// ================= prep: split fp32 -> bf16 hi/lo ==================
__global__ void split_x_kernel(const float* __restrict__ x,
                               unsigned short* __restrict__ hhi,
                               unsigned short* __restrict__ hlo)
{
    int i = blockIdx.x * blockDim.x + threadIdx.x;   // float4 index
    if (i >= (N_NODES * D) / 4) return;
    float4 v = ((const float4*)x)[i];
    unsigned short h0 = f2bf_rne(v.x), h1 = f2bf_rne(v.y);
    unsigned short h2 = f2bf_rne(v.z), h3 = f2bf_rne(v.w);
    unsigned short l0 = f2bf_rne(v.x - bf2f(h0)), l1 = f2bf_rne(v.y - bf2f(h1));
    unsigned short l2 = f2bf_rne(v.z - bf2f(h2)), l3 = f2bf_rne(v.w - bf2f(h3));
    uint2 hw, lw;
    hw.x = (unsigned)h0 | ((unsigned)h1 << 16);
    hw.y = (unsigned)h2 | ((unsigned)h3 << 16);
    lw.x = (unsigned)l0 | ((unsigned)l1 << 16);
    lw.y = (unsigned)l2 | ((unsigned)l3 << 16);
    ((uint2*)hhi)[i] = hw;
    ((uint2*)hlo)[i] = lw;
}

// transpose + split weights: W[l][k][n] -> Wt[l][n][k] hi/lo for both mats
__global__ void prep_weights_kernel(const float* __restrict__ Wl,
                                    const float* __restrict__ Wr,
                                    unsigned short* __restrict__ wlh, unsigned short* __restrict__ wll,
                                    unsigned short* __restrict__ wrh, unsigned short* __restrict__ wrl)
{
    int idx = blockIdx.x * blockDim.x + threadIdx.x;
    if (idx >= NLAYERS * D * D) return;
    int l   = idx / (D * D);
    int rem = idx - l * D * D;
    int kk  = rem / D;
    int nn  = rem - kk * D;
    int tp  = l * D * D + nn * D + kk;
    float v = Wl[idx];
    unsigned short h = f2bf_rne(v);
    wlh[tp] = h;
    wll[tp] = f2bf_rne(v - bf2f(h));
    v = Wr[idx];
    h = f2bf_rne(v);
    wrh[tp] = h;
    wrl[tp] = f2bf_rne(v - bf2f(h));
}

// ================= CSR build ==================
__global__ void degree_kernel(const int* __restrict__ dstp, int* __restrict__ deg)
{
    int e = blockIdx.x * blockDim.x + threadIdx.x;
    if (e >= ET) return;
    int dt = (e < N_EDGES) ? dstp[e] : e - N_EDGES;
    atomicAdd(deg + dt, 1);
}

// hierarchical scan: per-block inclusive scan + block sums
__global__ void scan1_kernel(const int* __restrict__ deg,
                             int* __restrict__ incl, int* __restrict__ bsum)
{
    __shared__ int tmp[1024];
    int tid = threadIdx.x;
    int i = blockIdx.x * 1024 + tid;
    int v = (i < N_NODES) ? deg[i] : 0;
    tmp[tid] = v;
    __syncthreads();
    #pragma unroll
    for (int o = 1; o < 1024; o <<= 1) {
        int t = (tid >= o) ? tmp[tid - o] : 0;
        __syncthreads();
        tmp[tid] += t;
        __syncthreads();
    }
    if (i < N_NODES) incl[i] = tmp[tid];
    if (tid == 1023) bsum[blockIdx.x] = tmp[1023];
}

// one wave: exclusive scan of the NB_SCAN block sums (+ total at bsum[NB_SCAN])
__global__ void scan2_kernel(int* __restrict__ bsum)
{
    int lane = threadIdx.x;
    int v = (lane < NB_SCAN) ? bsum[lane] : 0;
    int orig = v;
    #pragma unroll
    for (int o = 1; o < 64; o <<= 1) {
        int t = __shfl_up(v, o, 64);
        if (lane >= o) v += t;
    }
    if (lane < NB_SCAN) bsum[lane] = v - orig;    // exclusive
    if (lane == 63)     bsum[NB_SCAN] = v;        // grand total
}

// finalize: off[] (exclusive global) and cursor[] copy
__global__ void scan3_kernel(const int* __restrict__ deg, const int* __restrict__ incl,
                             const int* __restrict__ bsum,
                             int* __restrict__ off, int* __restrict__ cursor)
{
    int i = blockIdx.x * blockDim.x + threadIdx.x;
    if (i < N_NODES) {
        int e = incl[i] - deg[i] + bsum[i >> 10];
        off[i] = e;
        cursor[i] = e;
    } else if (i == N_NODES) {
        off[N_NODES] = bsum[NB_SCAN];
    }
}

__global__ void scatter_kernel(const int* __restrict__ srcp, const int* __restrict__ dstp,
                               int* __restrict__ cursor, int* __restrict__ esrc)
{
    int e = blockIdx.x * blockDim.x + threadIdx.x;
    if (e >= ET) return;
    int s, dt;
    if (e < N_EDGES) { s = srcp[e]; dt = dstp[e]; }
    else             { s = e - N_EDGES; dt = s; }
    int pos = atomicAdd(cursor + dt, 1);
    esrc[pos] = s;
}

// ============ MFMA dual GEMM, 3-term bf16x2 (~fp32 accuracy) ============
// xlb = bf16(h*Wl + bl)  [gathered later -> keep small], xr = fp32 (dst-local)
__global__ void gemm_mfma_kernel(const unsigned short* __restrict__ hhi,
                                 const unsigned short* __restrict__ hlo,
                                 const unsigned short* __restrict__ wlh,
                                 const unsigned short* __restrict__ wll,
                                 const unsigned short* __restrict__ wrh,
                                 const unsigned short* __restrict__ wrl,
                                 const float* __restrict__ bl, const float* __restrict__ br,
                                 unsigned short* __restrict__ xlb, float* __restrict__ xr, int n)
{
    int lane = threadIdx.x & 63;
    int wid  = threadIdx.x >> 6;
    int m0 = (blockIdx.x * 4 + wid) * 16;
    if (m0 >= n) return;
    int gl = lane & 15;
    int kg = lane >> 4;

    // A fragments: A[m][k], m = lane&15, k = (lane>>4)*8 + e
    int arow = m0 + gl; if (arow >= n) arow = n - 1;
    const unsigned short* ah = hhi + (size_t)arow * D + kg * 8;
    const unsigned short* al = hlo + (size_t)arow * D + kg * 8;
    bf16x8 Ah[4], Al[4];
    #pragma unroll
    for (int ks = 0; ks < 4; ks++) {
        Ah[ks] = *(const bf16x8*)(ah + ks * 32);
        Al[ks] = *(const bf16x8*)(al + ks * 32);
    }

    #pragma unroll
    for (int nt = 0; nt < 8; nt++) {
        int n0 = nt * 16;
        size_t boff = (size_t)(n0 + gl) * D + kg * 8;
        f32x4 accl = {0.f, 0.f, 0.f, 0.f};
        f32x4 accr = {0.f, 0.f, 0.f, 0.f};
        #pragma unroll
        for (int ks = 0; ks < 4; ks++) {
            bf16x8 Blh = *(const bf16x8*)(wlh + boff + ks * 32);
            bf16x8 Bll = *(const bf16x8*)(wll + boff + ks * 32);
            bf16x8 Brh = *(const bf16x8*)(wrh + boff + ks * 32);
            bf16x8 Brl = *(const bf16x8*)(wrl + boff + ks * 32);
            accl = __builtin_amdgcn_mfma_f32_16x16x32_bf16(Ah[ks], Blh, accl, 0, 0, 0);
            accl = __builtin_amdgcn_mfma_f32_16x16x32_bf16(Al[ks], Blh, accl, 0, 0, 0);
            accl = __builtin_amdgcn_mfma_f32_16x16x32_bf16(Ah[ks], Bll, accl, 0, 0, 0);
            accr = __builtin_amdgcn_mfma_f32_16x16x32_bf16(Ah[ks], Brh, accr, 0, 0, 0);
            accr = __builtin_amdgcn_mfma_f32_16x16x32_bf16(Al[ks], Brh, accr, 0, 0, 0);
            accr = __builtin_amdgcn_mfma_f32_16x16x32_bf16(Ah[ks], Brl, accr, 0, 0, 0);
        }
        float blc = bl[n0 + gl], brc = br[n0 + gl];
        // C/D layout: col = lane&15, row = (lane>>4)*4 + reg
        #pragma unroll
        for (int r = 0; r < 4; r++) {
            int row = m0 + kg * 4 + r;
            if (row < n) {
                xlb[(size_t)row * D + n0 + gl] = f2bf_rne(accl[r] + blc);
                xr [(size_t)row * D + n0 + gl] = accr[r] + brc;
            }
        }
    }
}

// ============ fused per-node GATv2: 4 edges/wave, 16 lanes/edge, bf16 gather ========
// LAST=1: fuse log_softmax, write fp32 out. LAST=0: write h as bf16 hi/lo.
template <int LAST>
__global__ void node_attn_kernel(const unsigned short* __restrict__ xlb,
                                 const float* __restrict__ xr,
                                 const float* __restrict__ att,
                                 const float* __restrict__ bias,
                                 const int* __restrict__ off,
                                 const int* __restrict__ esrc,
                                 float* __restrict__ outF,
                                 unsigned short* __restrict__ hhi,
                                 unsigned short* __restrict__ hlo)
{
    int i    = (int)((blockIdx.x * (size_t)blockDim.x + threadIdx.x) >> 6);
    int lane = threadIdx.x & 63;
    if (i >= N_NODES) return;
    int g  = lane >> 4;     // edge slot 0..3
    int gl = lane & 15;     // lane within group
    int fb = gl * 8;        // this lane's 8 features

    float4 aa = *(const float4*)(att + fb);
    float4 ab = *(const float4*)(att + fb + 4);
    const float* xri = xr + (size_t)i * D + fb;
    float4 ra = *(const float4*)(xri);
    float4 rb = *(const float4*)(xri + 4);

    float m = -1e30f, l = 0.f;
    float acc[8];
    #pragma unroll
    for (int e = 0; e < 8; e++) acc[e] = 0.f;

    int k    = off[i];
    int kEnd = off[i + 1];

    int kk = k + g;
    bool valid = kk < kEnd;
    int s0 = esrc[valid ? kk : kEnd - 1];
    uint4 x4 = *(const uint4*)(xlb + (size_t)s0 * D + fb);

    while (k < kEnd) {
        int kn = k + 4;
        uint4 nx4 = x4;
        bool nvalid = false;
        if (kn < kEnd) {                       // wave-uniform branch: prefetch
            int nkk = kn + g;
            nvalid = nkk < kEnd;
            int ns = esrc[nvalid ? nkk : kEnd - 1];
            nx4 = *(const uint4*)(xlb + (size_t)ns * D + fb);
        }
        // unpack 8 bf16 (2 bit-ops per pair)
        float x0 = __uint_as_float(x4.x << 16), x1 = __uint_as_float(x4.x & 0xffff0000u);
        float x2 = __uint_as_float(x4.y << 16), x3 = __uint_as_float(x4.y & 0xffff0000u);
        float x4f = __uint_as_float(x4.z << 16), x5 = __uint_as_float(x4.z & 0xffff0000u);
        float x6 = __uint_as_float(x4.w << 16), x7 = __uint_as_float(x4.w & 0xffff0000u);
        // score partial over this lane's 8 features
        float v, sc;
        v = x0  + ra.x; v = v > 0.f ? v : SLOPE * v; sc  = v * aa.x;
        v = x1  + ra.y; v = v > 0.f ? v : SLOPE * v; sc += v * aa.y;
        v = x2  + ra.z; v = v > 0.f ? v : SLOPE * v; sc += v * aa.z;
        v = x3  + ra.w; v = v > 0.f ? v : SLOPE * v; sc += v * aa.w;
        v = x4f + rb.x; v = v > 0.f ? v : SLOPE * v; sc += v * ab.x;
        v = x5  + rb.y; v = v > 0.f ? v : SLOPE * v; sc += v * ab.y;
        v = x6  + rb.z; v = v > 0.f ? v : SLOPE * v; sc += v * ab.z;
        v = x7  + rb.w; v = v > 0.f ? v : SLOPE * v; sc += v * ab.w;
        sc += __shfl_xor(sc, 1, 64);
        sc += __shfl_xor(sc, 2, 64);
        sc += __shfl_xor(sc, 4, 64);
        sc += __shfl_xor(sc, 8, 64);
        // online softmax update
        float mn = fmaxf(m, sc);
        float p  = valid ? __expf(sc - mn) : 0.f;
        float f  = __expf(m - mn);
        l = l * f + p;
        acc[0] = acc[0] * f + p * x0;
        acc[1] = acc[1] * f + p * x1;
        acc[2] = acc[2] * f + p * x2;
        acc[3] = acc[3] * f + p * x3;
        acc[4] = acc[4] * f + p * x4f;
        acc[5] = acc[5] * f + p * x5;
        acc[6] = acc[6] * f + p * x6;
        acc[7] = acc[7] * f + p * x7;
        m = mn;
        x4 = nx4; valid = nvalid;
        k = kn;
    }

    // merge the 4 groups' online-softmax states
    #pragma unroll
    for (int o = 16; o <= 32; o <<= 1) {
        float mo  = __shfl_xor(m, o, 64);
        float lo2 = __shfl_xor(l, o, 64);
        float mn  = fmaxf(m, mo);
        float f1  = __expf(m - mn);
        float f2  = __expf(mo - mn);
        l = l * f1 + lo2 * f2;
        #pragma unroll
        for (int e = 0; e < 8; e++) {
            float ao = __shfl_xor(acc[e], o, 64);
            acc[e] = acc[e] * f1 + ao * f2;
        }
        m = mn;
    }

    float inv = 1.f / (l + 1e-16f);
    const float* bp = bias + fb;
    float4 ba = *(const float4*)(bp);
    float4 bb = *(const float4*)(bp + 4);
    float hv[8];
    hv[0] = fmaxf(acc[0] * inv + ba.x, 0.f);
    hv[1] = fmaxf(acc[1] * inv + ba.y, 0.f);
    hv[2] = fmaxf(acc[2] * inv + ba.z, 0.f);
    hv[3] = fmaxf(acc[3] * inv + ba.w, 0.f);
    hv[4] = fmaxf(acc[4] * inv + bb.x, 0.f);
    hv[5] = fmaxf(acc[5] * inv + bb.y, 0.f);
    hv[6] = fmaxf(acc[6] * inv + bb.z, 0.f);
    hv[7] = fmaxf(acc[7] * inv + bb.w, 0.f);

    if (LAST) {
        float mx = hv[0];
        #pragma unroll
        for (int e = 1; e < 8; e++) mx = fmaxf(mx, hv[e]);
        mx = fmaxf(mx, __shfl_xor(mx, 1, 64));
        mx = fmaxf(mx, __shfl_xor(mx, 2, 64));
        mx = fmaxf(mx, __shfl_xor(mx, 4, 64));
        mx = fmaxf(mx, __shfl_xor(mx, 8, 64));
        float se = 0.f;
        #pragma unroll
        for (int e = 0; e < 8; e++) se += __expf(hv[e] - mx);
        se += __shfl_xor(se, 1, 64);
        se += __shfl_xor(se, 2, 64);
        se += __shfl_xor(se, 4, 64);
        se += __shfl_xor(se, 8, 64);
        float ls = logf(se) + mx;
        if (g == 0) {
            float4 o0 = make_float4(hv[0] - ls, hv[1] - ls, hv[2] - ls, hv[3] - ls);
            float4 o1 = make_float4(hv[4] - ls, hv[5] - ls, hv[6] - ls, hv[7] - ls);
            float* dst = outF + (size_t)i * D + fb;
            *(float4*)(dst)     = o0;
            *(float4*)(dst + 4) = o1;
        }
    } else {
        if (g < 2) {
            unsigned short w16[8];
            #pragma unroll
            for (int e = 0; e < 8; e++) {
                unsigned short hb = f2bf_rne(hv[e]);
                if (g == 0) w16[e] = hb;
                else        w16[e] = f2bf_rne(hv[e] - bf2f(hb));
            }
            uint4 pk;
            pk.x = (unsigned)w16[0] | ((unsigned)w16[1] << 16);
            pk.y = (unsigned)w16[2] | ((unsigned)w16[3] << 16);
            pk.z = (unsigned)w16[4] | ((unsigned)w16[5] << 16);
            pk.w = (unsigned)w16[6] | ((unsigned)w16[7] << 16);
            unsigned short* dst = (g == 0 ? hhi : hlo) + (size_t)i * D + fb;
            *(uint4*)dst = pk;
        }
    }
}

extern "C" void kernel_launch(void* const* d_in, const int* in_sizes, int n_in,
                              void* d_out, int out_size, void* d_ws, size_t ws_size,
                              hipStream_t stream)
{
    const float* x    = (const float*)d_in[0];
    const int*   ei   = (const int*)  d_in[1];
    const float* Wl   = (const float*)d_in[2];
    const float* bl   = (const float*)d_in[3];
    const float* Wr   = (const float*)d_in[4];
    const float* br   = (const float*)d_in[5];
    const float* att  = (const float*)d_in[6];
    const float* bias = (const float*)d_in[7];
    float* out = (float*)d_out;

    const int* srcp = ei;
    const int* dstp = ei + N_EDGES;

    const size_t ND = (size_t)N_NODES * D;
    const size_t WSZ = (size_t)NLAYERS * D * D;
    char* ws = (char*)d_ws;
    unsigned short* xlb = (unsigned short*)ws; ws += ND * sizeof(unsigned short);
    float* xr  = (float*)ws;                   ws += ND * sizeof(float);
    unsigned short* hhi = (unsigned short*)ws; ws += ND * sizeof(unsigned short);
    unsigned short* hlo = (unsigned short*)ws; ws += ND * sizeof(unsigned short);
    unsigned short* wlh = (unsigned short*)ws; ws += WSZ * sizeof(unsigned short);
    unsigned short* wll = (unsigned short*)ws; ws += WSZ * sizeof(unsigned short);
    unsigned short* wrh = (unsigned short*)ws; ws += WSZ * sizeof(unsigned short);
    unsigned short* wrl = (unsigned short*)ws; ws += WSZ * sizeof(unsigned short);
    int* deg    = (int*)ws;  ws += (size_t)N_NODES * sizeof(int);
    int* incl   = (int*)ws;  ws += (size_t)N_NODES * sizeof(int);
    int* off    = (int*)ws;  ws += (size_t)(N_NODES + 1) * sizeof(int);
    int* cursor = (int*)ws;  ws += (size_t)N_NODES * sizeof(int);
    int* bsum   = (int*)ws;  ws += (size_t)(NB_SCAN + 1) * sizeof(int);
    int* esrc   = (int*)ws;  ws += (size_t)ET * sizeof(int);

    const int splitGrid = (int)((ND / 4 + 255) / 256);
    const int wGrid     = (int)((WSZ + 255) / 256);
    const int edgeGrid  = (ET + 255) / 256;
    const int gemmGrid  = (N_NODES + 63) / 64;
    const int nodeGrid  = (N_NODES + 3) / 4;

    // prep (independent of CSR)
    split_x_kernel<<<splitGrid, 256, 0, stream>>>(x, hhi, hlo);
    prep_weights_kernel<<<wGrid, 256, 0, stream>>>(Wl, Wr, wlh, wll, wrh, wrl);

    // CSR build (hierarchical scan)
    hipMemsetAsync(deg, 0, (size_t)N_NODES * sizeof(int), stream);
    degree_kernel<<<edgeGrid, 256, 0, stream>>>(dstp, deg);
    scan1_kernel<<<NB_SCAN, 1024, 0, stream>>>(deg, incl, bsum);
    scan2_kernel<<<1, 64, 0, stream>>>(bsum);
    scan3_kernel<<<(N_NODES + 256) / 256, 256, 0, stream>>>(deg, incl, bsum, off, cursor);
    scatter_kernel<<<edgeGrid, 256, 0, stream>>>(srcp, dstp, cursor, esrc);

    for (int l = 0; l < NLAYERS; l++) {
        size_t wOff = (size_t)l * D * D;
        gemm_mfma_kernel<<<gemmGrid, 256, 0, stream>>>(
            hhi, hlo, wlh + wOff, wll + wOff, wrh + wOff, wrl + wOff,
            bl + (size_t)l * D, br + (size_t)l * D, xlb, xr, N_NODES);

        if (l == NLAYERS - 1) {
            node_attn_kernel<1><<<nodeGrid, 256, 0, stream>>>(
                xlb, xr, att + (size_t)l * D, bias + (size_t)l * D,
                off, esrc, out, nullptr, nullptr);
        } else {
            node_attn_kernel<0><<<nodeGrid, 256, 0, stream>>>(
                xlb, xr, att + (size_t)l * D, bias + (size_t)l * D,
                off, esrc, nullptr, hhi, hlo);
        }
    }
}

// Round 5
// 424.585 us; speedup vs baseline: 4.6153x; 1.1332x over previous
//
#include <hip/hip_runtime.h>
#include <cstdint>
#include <cstddef>

#define N_NODES 50000
#define N_EDGES 800000
#define ET (N_EDGES + N_NODES)   // edges + self loops
#define D 128
#define NLAYERS 3
#define SLOPE 0.2f
#define NB_SCAN ((N_NODES + 1023) / 1024)   // 49 blocks

typedef __bf16 bf16x8 __attribute__((ext_vector_type(8)));
typedef float  f32x4  __attribute__((ext_vector_type(4)));

// ---- bf16 split helpers (round-to-nearest-even) ----
__device__ __forceinline__ unsigned short f2bf_rne(float v) {
    unsigned u = __float_as_uint(v);
    u += 0x7fffu + ((u >> 16) & 1u);
    return (unsigned short)(u >> 16);
}
__device__ __forceinline__ float bf2f(unsigned short h) {
    return __uint_as_float(((unsigned)h) << 16);
}

// ================= prep: split fp32 -> bf16 hi/lo ==================
__global__ void split_x_kernel(const float* __restrict__ x,
                               unsigned short* __restrict__ hhi,
                               unsigned short* __restrict__ hlo)
{
    int i = blockIdx.x * blockDim.x + threadIdx.x;   // float4 index
    if (i >= (N_NODES * D) / 4) return;
    float4 v = ((const float4*)x)[i];
    unsigned short h0 = f2bf_rne(v.x), h1 = f2bf_rne(v.y);
    unsigned short h2 = f2bf_rne(v.z), h3 = f2bf_rne(v.w);
    unsigned short l0 = f2bf_rne(v.x - bf2f(h0)), l1 = f2bf_rne(v.y - bf2f(h1));
    unsigned short l2 = f2bf_rne(v.z - bf2f(h2)), l3 = f2bf_rne(v.w - bf2f(h3));
    uint2 hw, lw;
    hw.x = (unsigned)h0 | ((unsigned)h1 << 16);
    hw.y = (unsigned)h2 | ((unsigned)h3 << 16);
    lw.x = (unsigned)l0 | ((unsigned)l1 << 16);
    lw.y = (unsigned)l2 | ((unsigned)l3 << 16);
    ((uint2*)hhi)[i] = hw;
    ((uint2*)hlo)[i] = lw;
}

// transpose + split weights: W[l][k][n] -> Wt[l][n][k] hi/lo for both mats
__global__ void prep_weights_kernel(const float* __restrict__ Wl,
                                    const float* __restrict__ Wr,
                                    unsigned short* __restrict__ wlh, unsigned short* __restrict__ wll,
                                    unsigned short* __restrict__ wrh, unsigned short* __restrict__ wrl)
{
    int idx = blockIdx.x * blockDim.x + threadIdx.x;
    if (idx >= NLAYERS * D * D) return;
    int l   = idx / (D * D);
    int rem = idx - l * D * D;
    int kk  = rem / D;
    int nn  = rem - kk * D;
    int tp  = l * D * D + nn * D + kk;
    float v = Wl[idx];
    unsigned short h = f2bf_rne(v);
    wlh[tp] = h;
    wll[tp] = f2bf_rne(v - bf2f(h));
    v = Wr[idx];
    h = f2bf_rne(v);
    wrh[tp] = h;
    wrl[tp] = f2bf_rne(v - bf2f(h));
}

// ================= CSR build ==================
__global__ void degree_kernel(const int* __restrict__ dstp, int* __restrict__ deg)
{
    int e = blockIdx.x * blockDim.x + threadIdx.x;
    if (e >= ET) return;
    int dt = (e < N_EDGES) ? dstp[e] : e - N_EDGES;
    atomicAdd(deg + dt, 1);
}

// hierarchical scan: per-block inclusive scan + block sums
__global__ void scan1_kernel(const int* __restrict__ deg,
                             int* __restrict__ incl, int* __restrict__ bsum)
{
    __shared__ int tmp[1024];
    int tid = threadIdx.x;
    int i = blockIdx.x * 1024 + tid;
    int v = (i < N_NODES) ? deg[i] : 0;
    tmp[tid] = v;
    __syncthreads();
    #pragma unroll
    for (int o = 1; o < 1024; o <<= 1) {
        int t = (tid >= o) ? tmp[tid - o] : 0;
        __syncthreads();
        tmp[tid] += t;
        __syncthreads();
    }
    if (i < N_NODES) incl[i] = tmp[tid];
    if (tid == 1023) bsum[blockIdx.x] = tmp[1023];
}

// one wave: exclusive scan of the NB_SCAN block sums (+ total at bsum[NB_SCAN])
__global__ void scan2_kernel(int* __restrict__ bsum)
{
    int lane = threadIdx.x;
    int v = (lane < NB_SCAN) ? bsum[lane] : 0;
    int orig = v;
    #pragma unroll
    for (int o = 1; o < 64; o <<= 1) {
        int t = __shfl_up(v, o, 64);
        if (lane >= o) v += t;
    }
    if (lane < NB_SCAN) bsum[lane] = v - orig;    // exclusive
    if (lane == 63)     bsum[NB_SCAN] = v;        // grand total
}

// finalize: off[] (exclusive global) and cursor[] copy
__global__ void scan3_kernel(const int* __restrict__ deg, const int* __restrict__ incl,
                             const int* __restrict__ bsum,
                             int* __restrict__ off, int* __restrict__ cursor)
{
    int i = blockIdx.x * blockDim.x + threadIdx.x;
    if (i < N_NODES) {
        int e = incl[i] - deg[i] + bsum[i >> 10];
        off[i] = e;
        cursor[i] = e;
    } else if (i == N_NODES) {
        off[N_NODES] = bsum[NB_SCAN];
    }
}

__global__ void scatter_kernel(const int* __restrict__ srcp, const int* __restrict__ dstp,
                               int* __restrict__ cursor, int* __restrict__ esrc)
{
    int e = blockIdx.x * blockDim.x + threadIdx.x;
    if (e >= ET) return;
    int s, dt;
    if (e < N_EDGES) { s = srcp[e]; dt = dstp[e]; }
    else             { s = e - N_EDGES; dt = s; }
    int pos = atomicAdd(cursor + dt, 1);
    esrc[pos] = s;
}

// ============ MFMA dual GEMM, 3-term bf16x2, register-blocked + B double-buffer ======
// Wave tile: 32 rows x 64 cols. Block = 4 waves = 128 rows; grid = rowBlocks x 2 colHalves.
#define LOADB(BLH, BLL, BRH, BRL, n0)                                     \
    {   size_t boff = (size_t)((n0) + gl) * D + kg * 8;                   \
        _Pragma("unroll")                                                 \
        for (int ks = 0; ks < 4; ks++) {                                  \
            BLH[ks] = *(const bf16x8*)(wlh + boff + ks * 32);             \
            BLL[ks] = *(const bf16x8*)(wll + boff + ks * 32);             \
            BRH[ks] = *(const bf16x8*)(wrh + boff + ks * 32);             \
            BRL[ks] = *(const bf16x8*)(wrl + boff + ks * 32);             \
        } }

#define COMPUTE(BLH, BLL, BRH, BRL, n0)                                              \
    {   f32x4 accl0 = {0.f,0.f,0.f,0.f}, accr0 = {0.f,0.f,0.f,0.f};                  \
        f32x4 accl1 = {0.f,0.f,0.f,0.f}, accr1 = {0.f,0.f,0.f,0.f};                  \
        _Pragma("unroll")                                                            \
        for (int ks = 0; ks < 4; ks++) {                                             \
            accl0 = __builtin_amdgcn_mfma_f32_16x16x32_bf16(Ah0[ks], BLH[ks], accl0, 0, 0, 0); \
            accl0 = __builtin_amdgcn_mfma_f32_16x16x32_bf16(Al0[ks], BLH[ks], accl0, 0, 0, 0); \
            accl0 = __builtin_amdgcn_mfma_f32_16x16x32_bf16(Ah0[ks], BLL[ks], accl0, 0, 0, 0); \
            accr0 = __builtin_amdgcn_mfma_f32_16x16x32_bf16(Ah0[ks], BRH[ks], accr0, 0, 0, 0); \
            accr0 = __builtin_amdgcn_mfma_f32_16x16x32_bf16(Al0[ks], BRH[ks], accr0, 0, 0, 0); \
            accr0 = __builtin_amdgcn_mfma_f32_16x16x32_bf16(Ah0[ks], BRL[ks], accr0, 0, 0, 0); \
            accl1 = __builtin_amdgcn_mfma_f32_16x16x32_bf16(Ah1[ks], BLH[ks], accl1, 0, 0, 0); \
            accl1 = __builtin_amdgcn_mfma_f32_16x16x32_bf16(Al1[ks], BLH[ks], accl1, 0, 0, 0); \
            accl1 = __builtin_amdgcn_mfma_f32_16x16x32_bf16(Ah1[ks], BLL[ks], accl1, 0, 0, 0); \
            accr1 = __builtin_amdgcn_mfma_f32_16x16x32_bf16(Ah1[ks], BRH[ks], accr1, 0, 0, 0); \
            accr1 = __builtin_amdgcn_mfma_f32_16x16x32_bf16(Al1[ks], BRH[ks], accr1, 0, 0, 0); \
            accr1 = __builtin_amdgcn_mfma_f32_16x16x32_bf16(Ah1[ks], BRL[ks], accr1, 0, 0, 0); \
        }                                                                            \
        float blc = bl[(n0) + gl], brc = br[(n0) + gl];                              \
        _Pragma("unroll")                                                            \
        for (int r = 0; r < 4; r++) {                                                \
            int row0 = m0 + kg * 4 + r;                                              \
            if (row0 < n) {                                                          \
                xlb[(size_t)row0 * D + (n0) + gl] = f2bf_rne(accl0[r] + blc);        \
                xr [(size_t)row0 * D + (n0) + gl] = accr0[r] + brc;                  \
            }                                                                        \
            int row1 = m0 + 16 + kg * 4 + r;                                         \
            if (row1 < n) {                                                          \
                xlb[(size_t)row1 * D + (n0) + gl] = f2bf_rne(accl1[r] + blc);        \
                xr [(size_t)row1 * D + (n0) + gl] = accr1[r] + brc;                  \
            }                                                                        \
        } }

__global__ __launch_bounds__(256, 2)
void gemm_mfma_kernel(const unsigned short* __restrict__ hhi,
                      const unsigned short* __restrict__ hlo,
                      const unsigned short* __restrict__ wlh,
                      const unsigned short* __restrict__ wll,
                      const unsigned short* __restrict__ wrh,
                      const unsigned short* __restrict__ wrl,
                      const float* __restrict__ bl, const float* __restrict__ br,
                      unsigned short* __restrict__ xlb, float* __restrict__ xr, int n)
{
    int lane = threadIdx.x & 63;
    int wid  = threadIdx.x >> 6;          // 0..3
    int rowB = blockIdx.x >> 1;
    int c0   = (blockIdx.x & 1) * 64;     // column half
    int m0   = (rowB * 4 + wid) * 32;     // this wave's 32 rows
    if (m0 >= n) return;
    int gl = lane & 15;
    int kg = lane >> 4;

    // A fragments: 2 row-tiles x 4 ks x hi/lo, held in registers for the whole kernel
    int ar0 = m0 + gl;      if (ar0 >= n) ar0 = n - 1;
    int ar1 = m0 + 16 + gl; if (ar1 >= n) ar1 = n - 1;
    const unsigned short* ah0 = hhi + (size_t)ar0 * D + kg * 8;
    const unsigned short* al0 = hlo + (size_t)ar0 * D + kg * 8;
    const unsigned short* ah1 = hhi + (size_t)ar1 * D + kg * 8;
    const unsigned short* al1 = hlo + (size_t)ar1 * D + kg * 8;
    bf16x8 Ah0[4], Al0[4], Ah1[4], Al1[4];
    #pragma unroll
    for (int ks = 0; ks < 4; ks++) {
        Ah0[ks] = *(const bf16x8*)(ah0 + ks * 32);
        Al0[ks] = *(const bf16x8*)(al0 + ks * 32);
        Ah1[ks] = *(const bf16x8*)(ah1 + ks * 32);
        Al1[ks] = *(const bf16x8*)(al1 + ks * 32);
    }

    // B ping-pong buffers: compute nt with one while prefetching nt+1 into the other
    bf16x8 B0lh[4], B0ll[4], B0rh[4], B0rl[4];
    bf16x8 B1lh[4], B1ll[4], B1rh[4], B1rl[4];

    LOADB(B0lh, B0ll, B0rh, B0rl, c0);
    LOADB(B1lh, B1ll, B1rh, B1rl, c0 + 16);
    COMPUTE(B0lh, B0ll, B0rh, B0rl, c0);
    LOADB(B0lh, B0ll, B0rh, B0rl, c0 + 32);
    COMPUTE(B1lh, B1ll, B1rh, B1rl, c0 + 16);
    LOADB(B1lh, B1ll, B1rh, B1rl, c0 + 48);
    COMPUTE(B0lh, B0ll, B0rh, B0rl, c0 + 32);
    COMPUTE(B1lh, B1ll, B1rh, B1rl, c0 + 48);
}

// ============ fused per-node GATv2: 4 edges/wave, 16 lanes/edge, bf16 gather ========
// LAST=1: fuse log_softmax, write fp32 out. LAST=0: write h as bf16 hi/lo.
template <int LAST>
__global__ void node_attn_kernel(const unsigned short* __restrict__ xlb,
                                 const float* __restrict__ xr,
                                 const float* __restrict__ att,
                                 const float* __restrict__ bias,
                                 const int* __restrict__ off,
                                 const int* __restrict__ esrc,
                                 float* __restrict__ outF,
                                 unsigned short* __restrict__ hhi,
                                 unsigned short* __restrict__ hlo)
{
    int i    = (int)((blockIdx.x * (size_t)blockDim.x + threadIdx.x) >> 6);
    int lane = threadIdx.x & 63;
    if (i >= N_NODES) return;
    int g  = lane >> 4;     // edge slot 0..3
    int gl = lane & 15;     // lane within group
    int fb = gl * 8;        // this lane's 8 features

    float4 aa = *(const float4*)(att + fb);
    float4 ab = *(const float4*)(att + fb + 4);
    const float* xri = xr + (size_t)i * D + fb;
    float4 ra = *(const float4*)(xri);
    float4 rb = *(const float4*)(xri + 4);

    float m = -1e30f, l = 0.f;
    float acc[8];
    #pragma unroll
    for (int e = 0; e < 8; e++) acc[e] = 0.f;

    int k    = off[i];
    int kEnd = off[i + 1];

    int kk = k + g;
    bool valid = kk < kEnd;
    int s0 = esrc[valid ? kk : kEnd - 1];
    uint4 x4 = *(const uint4*)(xlb + (size_t)s0 * D + fb);

    while (k < kEnd) {
        int kn = k + 4;
        uint4 nx4 = x4;
        bool nvalid = false;
        if (kn < kEnd) {                       // wave-uniform branch: prefetch
            int nkk = kn + g;
            nvalid = nkk < kEnd;
            int ns = esrc[nvalid ? nkk : kEnd - 1];
            nx4 = *(const uint4*)(xlb + (size_t)ns * D + fb);
        }
        // unpack 8 bf16 (2 bit-ops per pair)
        float x0 = __uint_as_float(x4.x << 16), x1 = __uint_as_float(x4.x & 0xffff0000u);
        float x2 = __uint_as_float(x4.y << 16), x3 = __uint_as_float(x4.y & 0xffff0000u);
        float x4f = __uint_as_float(x4.z << 16), x5 = __uint_as_float(x4.z & 0xffff0000u);
        float x6 = __uint_as_float(x4.w << 16), x7 = __uint_as_float(x4.w & 0xffff0000u);
        // score partial over this lane's 8 features
        float v, sc;
        v = x0  + ra.x; v = v > 0.f ? v : SLOPE * v; sc  = v * aa.x;
        v = x1  + ra.y; v = v > 0.f ? v : SLOPE * v; sc += v * aa.y;
        v = x2  + ra.z; v = v > 0.f ? v : SLOPE * v; sc += v * aa.z;
        v = x3  + ra.w; v = v > 0.f ? v : SLOPE * v; sc += v * aa.w;
        v = x4f + rb.x; v = v > 0.f ? v : SLOPE * v; sc += v * ab.x;
        v = x5  + rb.y; v = v > 0.f ? v : SLOPE * v; sc += v * ab.y;
        v = x6  + rb.z; v = v > 0.f ? v : SLOPE * v; sc += v * ab.z;
        v = x7  + rb.w; v = v > 0.f ? v : SLOPE * v; sc += v * ab.w;
        sc += __shfl_xor(sc, 1, 64);
        sc += __shfl_xor(sc, 2, 64);
        sc += __shfl_xor(sc, 4, 64);
        sc += __shfl_xor(sc, 8, 64);
        // online softmax update
        float mn = fmaxf(m, sc);
        float p  = valid ? __expf(sc - mn) : 0.f;
        float f  = __expf(m - mn);
        l = l * f + p;
        acc[0] = acc[0] * f + p * x0;
        acc[1] = acc[1] * f + p * x1;
        acc[2] = acc[2] * f + p * x2;
        acc[3] = acc[3] * f + p * x3;
        acc[4] = acc[4] * f + p * x4f;
        acc[5] = acc[5] * f + p * x5;
        acc[6] = acc[6] * f + p * x6;
        acc[7] = acc[7] * f + p * x7;
        m = mn;
        x4 = nx4; valid = nvalid;
        k = kn;
    }

    // merge the 4 groups' online-softmax states
    #pragma unroll
    for (int o = 16; o <= 32; o <<= 1) {
        float mo  = __shfl_xor(m, o, 64);
        float lo2 = __shfl_xor(l, o, 64);
        float mn  = fmaxf(m, mo);
        float f1  = __expf(m - mn);
        float f2  = __expf(mo - mn);
        l = l * f1 + lo2 * f2;
        #pragma unroll
        for (int e = 0; e < 8; e++) {
            float ao = __shfl_xor(acc[e], o, 64);
            acc[e] = acc[e] * f1 + ao * f2;
        }
        m = mn;
    }

    float inv = 1.f / (l + 1e-16f);
    const float* bp = bias + fb;
    float4 ba = *(const float4*)(bp);
    float4 bb = *(const float4*)(bp + 4);
    float hv[8];
    hv[0] = fmaxf(acc[0] * inv + ba.x, 0.f);
    hv[1] = fmaxf(acc[1] * inv + ba.y, 0.f);
    hv[2] = fmaxf(acc[2] * inv + ba.z, 0.f);
    hv[3] = fmaxf(acc[3] * inv + ba.w, 0.f);
    hv[4] = fmaxf(acc[4] * inv + bb.x, 0.f);
    hv[5] = fmaxf(acc[5] * inv + bb.y, 0.f);
    hv[6] = fmaxf(acc[6] * inv + bb.z, 0.f);
    hv[7] = fmaxf(acc[7] * inv + bb.w, 0.f);

    if (LAST) {
        float mx = hv[0];
        #pragma unroll
        for (int e = 1; e < 8; e++) mx = fmaxf(mx, hv[e]);
        mx = fmaxf(mx, __shfl_xor(mx, 1, 64));
        mx = fmaxf(mx, __shfl_xor(mx, 2, 64));
        mx = fmaxf(mx, __shfl_xor(mx, 4, 64));
        mx = fmaxf(mx, __shfl_xor(mx, 8, 64));
        float se = 0.f;
        #pragma unroll
        for (int e = 0; e < 8; e++) se += __expf(hv[e] - mx);
        se += __shfl_xor(se, 1, 64);
        se += __shfl_xor(se, 2, 64);
        se += __shfl_xor(se, 4, 64);
        se += __shfl_xor(se, 8, 64);
        float ls = logf(se) + mx;
        if (g == 0) {
            float4 o0 = make_float4(hv[0] - ls, hv[1] - ls, hv[2] - ls, hv[3] - ls);
            float4 o1 = make_float4(hv[4] - ls, hv[5] - ls, hv[6] - ls, hv[7] - ls);
            float* dst = outF + (size_t)i * D + fb;
            *(float4*)(dst)     = o0;
            *(float4*)(dst + 4) = o1;
        }
    } else {
        if (g < 2) {
            unsigned short w16[8];
            #pragma unroll
            for (int e = 0; e < 8; e++) {
                unsigned short hb = f2bf_rne(hv[e]);
                if (g == 0) w16[e] = hb;
                else        w16[e] = f2bf_rne(hv[e] - bf2f(hb));
            }
            uint4 pk;
            pk.x = (unsigned)w16[0] | ((unsigned)w16[1] << 16);
            pk.y = (unsigned)w16[2] | ((unsigned)w16[3] << 16);
            pk.z = (unsigned)w16[4] | ((unsigned)w16[5] << 16);
            pk.w = (unsigned)w16[6] | ((unsigned)w16[7] << 16);
            unsigned short* dst = (g == 0 ? hhi : hlo) + (size_t)i * D + fb;
            *(uint4*)dst = pk;
        }
    }
}

extern "C" void kernel_launch(void* const* d_in, const int* in_sizes, int n_in,
                              void* d_out, int out_size, void* d_ws, size_t ws_size,
                              hipStream_t stream)
{
    const float* x    = (const float*)d_in[0];
    const int*   ei   = (const int*)  d_in[1];
    const float* Wl   = (const float*)d_in[2];
    const float* bl   = (const float*)d_in[3];
    const float* Wr   = (const float*)d_in[4];
    const float* br   = (const float*)d_in[5];
    const float* att  = (const float*)d_in[6];
    const float* bias = (const float*)d_in[7];
    float* out = (float*)d_out;

    const int* srcp = ei;
    const int* dstp = ei + N_EDGES;

    const size_t ND = (size_t)N_NODES * D;
    const size_t WSZ = (size_t)NLAYERS * D * D;
    char* ws = (char*)d_ws;
    unsigned short* xlb = (unsigned short*)ws; ws += ND * sizeof(unsigned short);
    float* xr  = (float*)ws;                   ws += ND * sizeof(float);
    unsigned short* hhi = (unsigned short*)ws; ws += ND * sizeof(unsigned short);
    unsigned short* hlo = (unsigned short*)ws; ws += ND * sizeof(unsigned short);
    unsigned short* wlh = (unsigned short*)ws; ws += WSZ * sizeof(unsigned short);
    unsigned short* wll = (unsigned short*)ws; ws += WSZ * sizeof(unsigned short);
    unsigned short* wrh = (unsigned short*)ws; ws += WSZ * sizeof(unsigned short);
    unsigned short* wrl = (unsigned short*)ws; ws += WSZ * sizeof(unsigned short);
    int* deg    = (int*)ws;  ws += (size_t)N_NODES * sizeof(int);
    int* incl   = (int*)ws;  ws += (size_t)N_NODES * sizeof(int);
    int* off    = (int*)ws;  ws += (size_t)(N_NODES + 1) * sizeof(int);
    int* cursor = (int*)ws;  ws += (size_t)N_NODES * sizeof(int);
    int* bsum   = (int*)ws;  ws += (size_t)(NB_SCAN + 1) * sizeof(int);
    int* esrc   = (int*)ws;  ws += (size_t)ET * sizeof(int);

    const int splitGrid = (int)((ND / 4 + 255) / 256);
    const int wGrid     = (int)((WSZ + 255) / 256);
    const int edgeGrid  = (ET + 255) / 256;
    const int gemmGrid  = ((N_NODES + 127) / 128) * 2;   // rowBlocks x 2 col halves
    const int nodeGrid  = (N_NODES + 3) / 4;

    // prep (independent of CSR)
    split_x_kernel<<<splitGrid, 256, 0, stream>>>(x, hhi, hlo);
    prep_weights_kernel<<<wGrid, 256, 0, stream>>>(Wl, Wr, wlh, wll, wrh, wrl);

    // CSR build (hierarchical scan)
    hipMemsetAsync(deg, 0, (size_t)N_NODES * sizeof(int), stream);
    degree_kernel<<<edgeGrid, 256, 0, stream>>>(dstp, deg);
    scan1_kernel<<<NB_SCAN, 1024, 0, stream>>>(deg, incl, bsum);
    scan2_kernel<<<1, 64, 0, stream>>>(bsum);
    scan3_kernel<<<(N_NODES + 256) / 256, 256, 0, stream>>>(deg, incl, bsum, off, cursor);
    scatter_kernel<<<edgeGrid, 256, 0, stream>>>(srcp, dstp, cursor, esrc);

    for (int l = 0; l < NLAYERS; l++) {
        size_t wOff = (size_t)l * D * D;
        gemm_mfma_kernel<<<gemmGrid, 256, 0, stream>>>(
            hhi, hlo, wlh + wOff, wll + wOff, wrh + wOff, wrl + wOff,
            bl + (size_t)l * D, br + (size_t)l * D, xlb, xr, N_NODES);

        if (l == NLAYERS - 1) {
            node_attn_kernel<1><<<nodeGrid, 256, 0, stream>>>(
                xlb, xr, att + (size_t)l * D, bias + (size_t)l * D,
                off, esrc, out, nullptr, nullptr);
        } else {
            node_attn_kernel<0><<<nodeGrid, 256, 0, stream>>>(
                xlb, xr, att + (size_t)l * D, bias + (size_t)l * D,
                off, esrc, nullptr, hhi, hlo);
        }
    }
}